// Round 8
// baseline (2561.729 us; speedup 1.0000x reference)
//
#include <hip/hip_runtime.h>
#include <hip/hip_bf16.h>

// R8: R7 (passing fp16-MFMA fused kernel) + three targeted fixes:
//  1. amdgpu_waves_per_eu(2,2): force 256-VGPR budget -> kill the weight-
//     fragment spills R7's counters exposed (WRITE_SIZE 109MB = 640B/thread
//     scratch, FETCH 1.45GB of scratch reloads in the recurrence chain).
//  2. Double-buffered h0 + barrier minimization: encoder 5->3, decoder 5->4
//     __syncthreads per step.
//  3. x_t register prefetch: next step's global load issued under compute.
// Structure/mappings identical to R7 (validated end-to-end). FP32 output.

using s16x8 = __attribute__((ext_vector_type(8))) short;
using h16x8 = __attribute__((ext_vector_type(8))) _Float16;
using f32x4 = __attribute__((ext_vector_type(4))) float;

#define DEV static __device__ __forceinline__

DEV unsigned short f2h(float f) {
  _Float16 h = (_Float16)f;  // RNE
  return __builtin_bit_cast(unsigned short, h);
}
DEV float h2f(short h) {
  return (float)__builtin_bit_cast(_Float16, (unsigned short)h);
}
DEV float sigm(float v) { return 1.0f / (1.0f + __expf(-v)); }
DEV float tanh_(float v) {
  float e = __expf(-2.0f * fabsf(v));
  float r = (1.0f - e) / (1.0f + e);
  return v < 0.0f ? -r : r;
}
DEV f32x4 mf(s16x8 a, s16x8 b, f32x4 c) {
  return __builtin_amdgcn_mfma_f32_16x16x32_f16(
      __builtin_bit_cast(h16x8, a), __builtin_bit_cast(h16x8, b), c, 0, 0, 0);
}
DEV f32x4 splat4(float v) { f32x4 r = {v, v, v, v}; return r; }

// byte offset into a [rows][128] fp16 buffer; 16 slots of 8 fp16 per row,
// slot XOR-swizzled by row&15 -> conflict-free ds_read_b128 down columns.
DEV int swz(int row, int slot) { return row * 256 + (((slot ^ row) & 15) << 4); }

// stage one row of a [*][128] fp32 weight matrix -> swizzled fp16 LDS row
DEV void stageWrow(const float* __restrict__ W, char* lds, int r) {
  const float4* p = (const float4*)(W + r * 128);
#pragma unroll
  for (int s = 0; s < 16; ++s) {
    float4 a = p[2 * s], b = p[2 * s + 1];
    s16x8 v;
    v[0] = (short)f2h(a.x); v[1] = (short)f2h(a.y);
    v[2] = (short)f2h(a.z); v[3] = (short)f2h(a.w);
    v[4] = (short)f2h(b.x); v[5] = (short)f2h(b.y);
    v[6] = (short)f2h(b.z); v[7] = (short)f2h(b.w);
    *(s16x8*)(lds + swz(r, s)) = v;
  }
}

// register B-fragment from a [512][128] fp32 matrix: col fixed, k = s*32+hi*8+j
DEV s16x8 ldWfrag128(const float* __restrict__ W, int col, int s, int hi) {
  const float4* p = (const float4*)(W + col * 128 + s * 32 + hi * 8);
  float4 a = p[0], b = p[1];
  s16x8 v;
  v[0] = (short)f2h(a.x); v[1] = (short)f2h(a.y);
  v[2] = (short)f2h(a.z); v[3] = (short)f2h(a.w);
  v[4] = (short)f2h(b.x); v[5] = (short)f2h(b.y);
  v[6] = (short)f2h(b.z); v[7] = (short)f2h(b.w);
  return v;
}
// K=16 matrix (x-projection), zero-padded to K=32: lanes hi>=2 hold zeros
DEV s16x8 ldWfrag16(const float* __restrict__ W, int col, int hi) {
  s16x8 v;
#pragma unroll
  for (int j = 0; j < 8; ++j) v[j] = 0;
  if (hi < 2) {
    const float4* p = (const float4*)(W + col * 16 + hi * 8);
    float4 a = p[0], b = p[1];
    v[0] = (short)f2h(a.x); v[1] = (short)f2h(a.y);
    v[2] = (short)f2h(a.z); v[3] = (short)f2h(a.w);
    v[4] = (short)f2h(b.x); v[5] = (short)f2h(b.y);
    v[6] = (short)f2h(b.z); v[7] = (short)f2h(b.w);
  }
  return v;
}

// A fragment from a swizzled [32][128] fp16 h-buffer
DEV s16x8 ldA(const char* buf, int rt, int ks, int lo, int hi) {
  return *(const s16x8*)(buf + swz(rt * 16 + lo, ks * 4 + hi));
}
// B fragment from the LDS-resident weight matrix
DEV s16x8 ldB(const char* wlds, int colbase, int ks, int lo, int hi) {
  return *(const s16x8*)(wlds + swz(colbase + lo, ks * 4 + hi));
}
// scatter one fp16 h value into the swizzled h-buffer
DEV void storeH(char* buf, int row, int col, unsigned short v) {
  int addr = row * 256 + ((((col >> 3) ^ row) & 15) << 4) + (col & 7) * 2;
  *(unsigned short*)(buf + addr) = v;
}
// LSTM pointwise: gates (i,f,g,o) -> update c, return fp16(h)
DEV unsigned short cellup(float gi, float gf, float gg, float go, float& c) {
  float i = sigm(gi), f = sigm(gf), g2 = tanh_(gg), o = sigm(go);
  c = f * c + i * g2;
  return f2h(o * tanh_(c));
}

#define SMEM_BYTES 126208

__global__ __attribute__((amdgpu_flat_work_group_size(512, 512),
                          amdgpu_waves_per_eu(2, 2)))
void fused_kernel(
    const float* __restrict__ x,
    const float* __restrict__ eWih0, const float* __restrict__ eWhh0,
    const float* __restrict__ ebih0, const float* __restrict__ ebhh0,
    const float* __restrict__ eWih1, const float* __restrict__ eWhh1,
    const float* __restrict__ ebih1, const float* __restrict__ ebhh1,
    const float* __restrict__ dWih0, const float* __restrict__ dWhh0,
    const float* __restrict__ dbih0, const float* __restrict__ dbhh0,
    const float* __restrict__ dWih1, const float* __restrict__ dWhh1,
    const float* __restrict__ dbih1, const float* __restrict__ dbhh1,
    const float* __restrict__ fcW, const float* __restrict__ fcb,
    float* __restrict__ out) {
  extern __shared__ char smem[];
  char* wL   = smem;                       // 98304: W_hh0 gates 0..2 swizzled
  char* h0B  = smem + 98304;               // 2 x 8192: h0 double buffer
  char* h1L  = smem + 114688;              // 8192
  char* xL   = smem + 122880;              // 2560 (32 rows * 80B, K pad to 32)
  float* inpL = (float*)(smem + 125440);   // 256: 32x2 fp32 decoder feedback
  char* fcwL = smem + 125696;              // 512: 2x128 fp16

  const int tid = threadIdx.x;
  const int w = tid >> 6, l = tid & 63, lo = l & 15, hi = l >> 4;
  const int row0 = blockIdx.x * 32;
  const int colb = w * 16;

  // ================= encoder phase =================
  if (tid < 384) stageWrow(eWhh0, wL, tid);
  {  // zero h0 (both bufs), h1, and x buffer (incl. K-padding)
    int4 z = make_int4(0, 0, 0, 0);
    int4* p = (int4*)h0B;
    for (int i = tid; i < 1536; i += 512) p[i] = z;  // h0B+h1L = 24KB
    int4* q = (int4*)xL;
    for (int i = tid; i < 160; i += 512) q[i] = z;
  }

  float b0[4], b1[4];
  s16x8 wg3[4], wx0[4], wi1[4][4], wh1[4][4];
#pragma unroll
  for (int g = 0; g < 4; ++g) {
    int col = g * 128 + colb + lo;
    b0[g] = ebih0[col] + ebhh0[col];
    b1[g] = ebih1[col] + ebhh1[col];
    wx0[g] = ldWfrag16(eWih0, col, hi);
#pragma unroll
    for (int s = 0; s < 4; ++s) {
      wi1[g][s] = ldWfrag128(eWih1, col, s, hi);
      wh1[g][s] = ldWfrag128(eWhh1, col, s, hi);
    }
  }
#pragma unroll
  for (int s = 0; s < 4; ++s) wg3[s] = ldWfrag128(eWhh0, 384 + colb + lo, s, hi);

  float c0s[2][4], c1s[2][4];
#pragma unroll
  for (int rt = 0; rt < 2; ++rt)
#pragma unroll
    for (int r = 0; r < 4; ++r) { c0s[rt][r] = 0.f; c1s[rt][r] = 0.f; }
  __syncthreads();

  const int xr = tid >> 4, xf = tid & 15;
  const float* xrow = x + (long long)(row0 + xr) * 1600 + xf;
  float xv = xrow[0];
  int cur = 0;

  for (int t = 0; t < 100; ++t) {
    *(unsigned short*)(xL + xr * 80 + xf * 2) = f2h(xv);
    __syncthreads();  // A: xL visible
    if (t < 99) xv = xrow[(t + 1) * 16];  // prefetch under compute

    char* h0r = h0B + cur * 8192;
    char* h0w = h0B + (cur ^ 1) * 8192;

    // ---- layer 0: g = x@Wih0^T + h0@Whh0^T + b0
    f32x4 acc[2][4];
#pragma unroll
    for (int g = 0; g < 4; ++g) { acc[0][g] = splat4(b0[g]); acc[1][g] = splat4(b0[g]); }
    {
      s16x8 a0 = *(const s16x8*)(xL + lo * 80 + hi * 16);
      s16x8 a1 = *(const s16x8*)(xL + (16 + lo) * 80 + hi * 16);
#pragma unroll
      for (int g = 0; g < 4; ++g) {
        acc[0][g] = mf(a0, wx0[g], acc[0][g]);
        acc[1][g] = mf(a1, wx0[g], acc[1][g]);
      }
    }
#pragma unroll
    for (int ks = 0; ks < 4; ++ks) {
      s16x8 a0 = ldA(h0r, 0, ks, lo, hi), a1 = ldA(h0r, 1, ks, lo, hi);
#pragma unroll
      for (int g = 0; g < 3; ++g) {
        s16x8 bb = ldB(wL, g * 128 + colb, ks, lo, hi);
        acc[0][g] = mf(a0, bb, acc[0][g]);
        acc[1][g] = mf(a1, bb, acc[1][g]);
      }
      acc[0][3] = mf(a0, wg3[ks], acc[0][3]);
      acc[1][3] = mf(a1, wg3[ks], acc[1][3]);
    }
    unsigned short hb[2][4];
#pragma unroll
    for (int rt = 0; rt < 2; ++rt)
#pragma unroll
      for (int r = 0; r < 4; ++r)
        hb[rt][r] = cellup(acc[rt][0][r], acc[rt][1][r], acc[rt][2][r], acc[rt][3][r], c0s[rt][r]);
    // write new h0 to the OTHER buffer: no pre-store barrier needed
#pragma unroll
    for (int rt = 0; rt < 2; ++rt)
#pragma unroll
      for (int r = 0; r < 4; ++r)
        storeH(h0w, rt * 16 + hi * 4 + r, colb + lo, hb[rt][r]);
    __syncthreads();  // B: h0-new visible

    // ---- layer 1: g = h0new@Wih1^T + h1@Whh1^T + b1
#pragma unroll
    for (int g = 0; g < 4; ++g) { acc[0][g] = splat4(b1[g]); acc[1][g] = splat4(b1[g]); }
#pragma unroll
    for (int s = 0; s < 8; ++s) {
      const char* src = (s < 4) ? h0w : h1L;
      int ks = s & 3;
      s16x8 a0 = ldA(src, 0, ks, lo, hi), a1 = ldA(src, 1, ks, lo, hi);
#pragma unroll
      for (int g = 0; g < 4; ++g) {
        s16x8 bb = (s < 4) ? wi1[g][ks] : wh1[g][ks];
        acc[0][g] = mf(a0, bb, acc[0][g]);
        acc[1][g] = mf(a1, bb, acc[1][g]);
      }
    }
#pragma unroll
    for (int rt = 0; rt < 2; ++rt)
#pragma unroll
      for (int r = 0; r < 4; ++r)
        hb[rt][r] = cellup(acc[rt][0][r], acc[rt][1][r], acc[rt][2][r], acc[rt][3][r], c1s[rt][r]);
    __syncthreads();  // C: all waves done reading old h1
#pragma unroll
    for (int rt = 0; rt < 2; ++rt)
#pragma unroll
      for (int r = 0; r < 4; ++r)
        storeH(h1L, rt * 16 + hi * 4 + r, colb + lo, hb[rt][r]);
    // no post-store barrier: next read of h1 is after next step's A and B
    cur ^= 1;
  }

  // ================= restage for decoder =================
  // (all waves are past C of t=99 -> wL reads done; h1 stores above are
  //  made visible by the barrier below)
  if (tid < 384) stageWrow(dWhh0, wL, tid);
  if (tid < 64) {  // dec_in = x[:, 99, :2] (fp32)
    int r = tid >> 1, o = tid & 1;
    inpL[r * 2 + o] = x[(long long)(row0 + r) * 1600 + 1584 + o];
  }
  if (tid < 256) {
    int o = tid >> 7, k = tid & 127;
    *(unsigned short*)(fcwL + o * 256 + k * 2) = f2h(fcW[o * 128 + k]);
  }
  float dwx[4][2];
#pragma unroll
  for (int g = 0; g < 4; ++g) {
    int col = g * 128 + colb + lo;
    b0[g] = dbih0[col] + dbhh0[col];
    b1[g] = dbih1[col] + dbhh1[col];
    dwx[g][0] = dWih0[col * 2 + 0];
    dwx[g][1] = dWih0[col * 2 + 1];
#pragma unroll
    for (int s = 0; s < 4; ++s) {
      wi1[g][s] = ldWfrag128(dWih1, col, s, hi);
      wh1[g][s] = ldWfrag128(dWhh1, col, s, hi);
    }
  }
#pragma unroll
  for (int s = 0; s < 4; ++s) wg3[s] = ldWfrag128(dWhh0, 384 + colb + lo, s, hi);
  float fb0 = fcb[0], fb1 = fcb[1];
  __syncthreads();

  // ================= decoder phase =================
  for (int t = 0; t < 60; ++t) {
    char* h0r = h0B + cur * 8192;
    char* h0w = h0B + (cur ^ 1) * 8192;

    // ---- layer 0: g = inp@dWih0^T (VALU fp32, K=2) + h0@dWhh0^T + b0
    f32x4 acc[2][4];
#pragma unroll
    for (int rt = 0; rt < 2; ++rt)
#pragma unroll
      for (int r = 0; r < 4; ++r) {
        float2 ip = *(const float2*)(inpL + (rt * 16 + hi * 4 + r) * 2);
#pragma unroll
        for (int g = 0; g < 4; ++g)
          acc[rt][g][r] = b0[g] + ip.x * dwx[g][0] + ip.y * dwx[g][1];
      }
#pragma unroll
    for (int ks = 0; ks < 4; ++ks) {
      s16x8 a0 = ldA(h0r, 0, ks, lo, hi), a1 = ldA(h0r, 1, ks, lo, hi);
#pragma unroll
      for (int g = 0; g < 3; ++g) {
        s16x8 bb = ldB(wL, g * 128 + colb, ks, lo, hi);
        acc[0][g] = mf(a0, bb, acc[0][g]);
        acc[1][g] = mf(a1, bb, acc[1][g]);
      }
      acc[0][3] = mf(a0, wg3[ks], acc[0][3]);
      acc[1][3] = mf(a1, wg3[ks], acc[1][3]);
    }
    unsigned short hb[2][4];
#pragma unroll
    for (int rt = 0; rt < 2; ++rt)
#pragma unroll
      for (int r = 0; r < 4; ++r)
        hb[rt][r] = cellup(acc[rt][0][r], acc[rt][1][r], acc[rt][2][r], acc[rt][3][r], c0s[rt][r]);
#pragma unroll
    for (int rt = 0; rt < 2; ++rt)
#pragma unroll
      for (int r = 0; r < 4; ++r)
        storeH(h0w, rt * 16 + hi * 4 + r, colb + lo, hb[rt][r]);
    __syncthreads();  // B: h0-new visible

    // ---- layer 1
#pragma unroll
    for (int g = 0; g < 4; ++g) { acc[0][g] = splat4(b1[g]); acc[1][g] = splat4(b1[g]); }
#pragma unroll
    for (int s = 0; s < 8; ++s) {
      const char* src = (s < 4) ? h0w : h1L;
      int ks = s & 3;
      s16x8 a0 = ldA(src, 0, ks, lo, hi), a1 = ldA(src, 1, ks, lo, hi);
#pragma unroll
      for (int g = 0; g < 4; ++g) {
        s16x8 bb = (s < 4) ? wi1[g][ks] : wh1[g][ks];
        acc[0][g] = mf(a0, bb, acc[0][g]);
        acc[1][g] = mf(a1, bb, acc[1][g]);
      }
    }
#pragma unroll
    for (int rt = 0; rt < 2; ++rt)
#pragma unroll
      for (int r = 0; r < 4; ++r)
        hb[rt][r] = cellup(acc[rt][0][r], acc[rt][1][r], acc[rt][2][r], acc[rt][3][r], c1s[rt][r]);
    __syncthreads();  // C: all waves done reading old h1
#pragma unroll
    for (int rt = 0; rt < 2; ++rt)
#pragma unroll
      for (int r = 0; r < 4; ++r)
        storeH(h1L, rt * 16 + hi * 4 + r, colb + lo, hb[rt][r]);
    __syncthreads();  // D: h1-new visible for FC

    // ---- FC head + feedback (waves 0,1: lane -> (row, o, k-half))
    if (w < 2) {
      int row = w * 16 + lo;
      int o = hi & 1, kh = hi >> 1;
      float sum = 0.f;
#pragma unroll
      for (int cc = 0; cc < 8; ++cc) {
        s16x8 hv = *(const s16x8*)(h1L + swz(row, kh * 8 + cc));
        s16x8 wv = *(const s16x8*)(fcwL + o * 256 + (kh * 8 + cc) * 16);
#pragma unroll
        for (int j = 0; j < 8; ++j) sum += h2f(hv[j]) * h2f(wv[j]);
      }
      sum += __shfl_xor(sum, 32, 64);
      if (l < 32) {
        float ov = sum + (o ? fb1 : fb0);
        inpL[row * 2 + o] = ov;  // fp32 feedback, matches reference carry
        out[((long long)(row0 + row) * 60 + t) * 2 + o] = ov;  // FP32 store
      }
    }
    __syncthreads();  // E: inpL visible for next step's layer 0
    cur ^= 1;
  }
}

extern "C" void kernel_launch(void* const* d_in, const int* in_sizes, int n_in,
                              void* d_out, int out_size, void* d_ws, size_t ws_size,
                              hipStream_t stream) {
  (void)in_sizes; (void)n_in; (void)out_size; (void)d_ws; (void)ws_size;
  const float* x      = (const float*)d_in[0];
  // d_in[1] = target_len (60), hardcoded
  const float* eWih0  = (const float*)d_in[2];
  const float* eWhh0  = (const float*)d_in[3];
  const float* ebih0  = (const float*)d_in[4];
  const float* ebhh0  = (const float*)d_in[5];
  const float* eWih1  = (const float*)d_in[6];
  const float* eWhh1  = (const float*)d_in[7];
  const float* ebih1  = (const float*)d_in[8];
  const float* ebhh1  = (const float*)d_in[9];
  const float* dWih0  = (const float*)d_in[10];
  const float* dWhh0  = (const float*)d_in[11];
  const float* dbih0  = (const float*)d_in[12];
  const float* dbhh0  = (const float*)d_in[13];
  const float* dWih1  = (const float*)d_in[14];
  const float* dWhh1  = (const float*)d_in[15];
  const float* dbih1  = (const float*)d_in[16];
  const float* dbhh1  = (const float*)d_in[17];
  const float* fcW    = (const float*)d_in[18];
  const float* fcb    = (const float*)d_in[19];
  float* out          = (float*)d_out;

  hipFuncSetAttribute(reinterpret_cast<const void*>(fused_kernel),
                      hipFuncAttributeMaxDynamicSharedMemorySize, SMEM_BYTES);

  fused_kernel<<<256, 512, SMEM_BYTES, stream>>>(
      x, eWih0, eWhh0, ebih0, ebhh0, eWih1, eWhh1, ebih1, ebhh1,
      dWih0, dWhh0, dbih0, dbhh0, dWih1, dWhh1, dbih1, dbhh1,
      fcW, fcb, out);
}

// Round 9
// 2458.448 us; speedup vs baseline: 1.0420x; 1.0420x over previous
//
#include <hip/hip_runtime.h>
#include <hip/hip_bf16.h>

// R9: R7 structure (fastest so far) with register-demand reduction:
//   - FULL W_hh0 (all 4 gates, 512 rows) lives in LDS (128KB); the wg3
//     register fragments are deleted (-16 VGPR).
//   - x_t register prefetch (hides global latency under compute).
// Rationale: gfx950 unified VGPR+AGPR budget is 256/wave at 2 waves/SIMD;
// R7/R8 demand ~290 forced ~100 regs of spill (FETCH 1.45GB of scratch
// reloads). Target demand ~240 -> no spill.
// LDS = 150784 B (R1 proved >=150KB dynamic LDS launches on this harness).

using s16x8 = __attribute__((ext_vector_type(8))) short;
using h16x8 = __attribute__((ext_vector_type(8))) _Float16;
using f32x4 = __attribute__((ext_vector_type(4))) float;

#define DEV static __device__ __forceinline__

DEV unsigned short f2h(float f) {
  _Float16 h = (_Float16)f;  // RNE
  return __builtin_bit_cast(unsigned short, h);
}
DEV float h2f(short h) {
  return (float)__builtin_bit_cast(_Float16, (unsigned short)h);
}
DEV float sigm(float v) { return 1.0f / (1.0f + __expf(-v)); }
DEV float tanh_(float v) {
  float e = __expf(-2.0f * fabsf(v));
  float r = (1.0f - e) / (1.0f + e);
  return v < 0.0f ? -r : r;
}
DEV f32x4 mf(s16x8 a, s16x8 b, f32x4 c) {
  return __builtin_amdgcn_mfma_f32_16x16x32_f16(
      __builtin_bit_cast(h16x8, a), __builtin_bit_cast(h16x8, b), c, 0, 0, 0);
}
DEV f32x4 splat4(float v) { f32x4 r = {v, v, v, v}; return r; }

// byte offset into a [rows][128] fp16 buffer; 16 slots of 8 fp16 per row,
// slot XOR-swizzled by row&15 -> conflict-free ds_read_b128 down columns.
DEV int swz(int row, int slot) { return row * 256 + (((slot ^ row) & 15) << 4); }

// stage one row of a [*][128] fp32 weight matrix -> swizzled fp16 LDS row
DEV void stageWrow(const float* __restrict__ W, char* lds, int r) {
  const float4* p = (const float4*)(W + r * 128);
#pragma unroll
  for (int s = 0; s < 16; ++s) {
    float4 a = p[2 * s], b = p[2 * s + 1];
    s16x8 v;
    v[0] = (short)f2h(a.x); v[1] = (short)f2h(a.y);
    v[2] = (short)f2h(a.z); v[3] = (short)f2h(a.w);
    v[4] = (short)f2h(b.x); v[5] = (short)f2h(b.y);
    v[6] = (short)f2h(b.z); v[7] = (short)f2h(b.w);
    *(s16x8*)(lds + swz(r, s)) = v;
  }
}

// register B-fragment from a [512][128] fp32 matrix: col fixed, k = s*32+hi*8+j
DEV s16x8 ldWfrag128(const float* __restrict__ W, int col, int s, int hi) {
  const float4* p = (const float4*)(W + col * 128 + s * 32 + hi * 8);
  float4 a = p[0], b = p[1];
  s16x8 v;
  v[0] = (short)f2h(a.x); v[1] = (short)f2h(a.y);
  v[2] = (short)f2h(a.z); v[3] = (short)f2h(a.w);
  v[4] = (short)f2h(b.x); v[5] = (short)f2h(b.y);
  v[6] = (short)f2h(b.z); v[7] = (short)f2h(b.w);
  return v;
}
// K=16 matrix (x-projection), zero-padded to K=32: lanes hi>=2 hold zeros
DEV s16x8 ldWfrag16(const float* __restrict__ W, int col, int hi) {
  s16x8 v;
#pragma unroll
  for (int j = 0; j < 8; ++j) v[j] = 0;
  if (hi < 2) {
    const float4* p = (const float4*)(W + col * 16 + hi * 8);
    float4 a = p[0], b = p[1];
    v[0] = (short)f2h(a.x); v[1] = (short)f2h(a.y);
    v[2] = (short)f2h(a.z); v[3] = (short)f2h(a.w);
    v[4] = (short)f2h(b.x); v[5] = (short)f2h(b.y);
    v[6] = (short)f2h(b.z); v[7] = (short)f2h(b.w);
  }
  return v;
}

// A fragment from a swizzled [32][128] fp16 h-buffer
DEV s16x8 ldA(const char* buf, int rt, int ks, int lo, int hi) {
  return *(const s16x8*)(buf + swz(rt * 16 + lo, ks * 4 + hi));
}
// B fragment from the LDS-resident weight matrix
DEV s16x8 ldB(const char* wlds, int colbase, int ks, int lo, int hi) {
  return *(const s16x8*)(wlds + swz(colbase + lo, ks * 4 + hi));
}
// scatter one fp16 h value into the swizzled h-buffer
DEV void storeH(char* buf, int row, int col, unsigned short v) {
  int addr = row * 256 + ((((col >> 3) ^ row) & 15) << 4) + (col & 7) * 2;
  *(unsigned short*)(buf + addr) = v;
}
// LSTM pointwise: gates (i,f,g,o) -> update c, return fp16(h)
DEV unsigned short cellup(float gi, float gf, float gg, float go, float& c) {
  float i = sigm(gi), f = sigm(gf), g2 = tanh_(gg), o = sigm(go);
  c = f * c + i * g2;
  return f2h(o * tanh_(c));
}

#define SMEM_BYTES 150784

__global__ __launch_bounds__(512, 2) void fused_kernel(
    const float* __restrict__ x,
    const float* __restrict__ eWih0, const float* __restrict__ eWhh0,
    const float* __restrict__ ebih0, const float* __restrict__ ebhh0,
    const float* __restrict__ eWih1, const float* __restrict__ eWhh1,
    const float* __restrict__ ebih1, const float* __restrict__ ebhh1,
    const float* __restrict__ dWih0, const float* __restrict__ dWhh0,
    const float* __restrict__ dbih0, const float* __restrict__ dbhh0,
    const float* __restrict__ dWih1, const float* __restrict__ dWhh1,
    const float* __restrict__ dbih1, const float* __restrict__ dbhh1,
    const float* __restrict__ fcW, const float* __restrict__ fcb,
    float* __restrict__ out) {
  extern __shared__ char smem[];
  char* wL   = smem;                       // 131072: FULL W_hh0 swizzled
  char* h0L  = smem + 131072;              // 8192
  char* h1L  = smem + 139264;              // 8192
  char* xL   = smem + 147456;              // 2560 (32 rows * 80B, K pad to 32)
  float* inpL = (float*)(smem + 150016);   // 256: 32x2 fp32 decoder feedback
  char* fcwL = smem + 150272;              // 512: 2x128 fp16

  const int tid = threadIdx.x;
  const int w = tid >> 6, l = tid & 63, lo = l & 15, hi = l >> 4;
  const int row0 = blockIdx.x * 32;
  const int colb = w * 16;

  // ================= encoder phase =================
  stageWrow(eWhh0, wL, tid);  // 512 threads, 512 rows
  {  // zero h0,h1 and x buffer (incl. K-padding)
    int4 z = make_int4(0, 0, 0, 0);
    int4* p = (int4*)h0L;
    for (int i = tid; i < 1024; i += 512) p[i] = z;
    int4* q = (int4*)xL;
    for (int i = tid; i < 160; i += 512) q[i] = z;
  }

  float b0[4], b1[4];
  s16x8 wx0[4], wi1[4][4], wh1[4][4];
#pragma unroll
  for (int g = 0; g < 4; ++g) {
    int col = g * 128 + colb + lo;
    b0[g] = ebih0[col] + ebhh0[col];
    b1[g] = ebih1[col] + ebhh1[col];
    wx0[g] = ldWfrag16(eWih0, col, hi);
#pragma unroll
    for (int s = 0; s < 4; ++s) {
      wi1[g][s] = ldWfrag128(eWih1, col, s, hi);
      wh1[g][s] = ldWfrag128(eWhh1, col, s, hi);
    }
  }

  float c0s[2][4], c1s[2][4];
#pragma unroll
  for (int rt = 0; rt < 2; ++rt)
#pragma unroll
    for (int r = 0; r < 4; ++r) { c0s[rt][r] = 0.f; c1s[rt][r] = 0.f; }
  __syncthreads();

  const int xr = tid >> 4, xf = tid & 15;
  const float* xrow = x + (long long)(row0 + xr) * 1600 + xf;
  float xv = xrow[0];

  for (int t = 0; t < 100; ++t) {
    *(unsigned short*)(xL + xr * 80 + xf * 2) = f2h(xv);
    __syncthreads();
    if (t < 99) xv = xrow[(t + 1) * 16];  // prefetch under compute

    // ---- layer 0: g = x@Wih0^T + h0@Whh0^T + b0
    f32x4 acc[2][4];
#pragma unroll
    for (int g = 0; g < 4; ++g) { acc[0][g] = splat4(b0[g]); acc[1][g] = splat4(b0[g]); }
    {
      s16x8 a0 = *(const s16x8*)(xL + lo * 80 + hi * 16);
      s16x8 a1 = *(const s16x8*)(xL + (16 + lo) * 80 + hi * 16);
#pragma unroll
      for (int g = 0; g < 4; ++g) {
        acc[0][g] = mf(a0, wx0[g], acc[0][g]);
        acc[1][g] = mf(a1, wx0[g], acc[1][g]);
      }
    }
#pragma unroll
    for (int ks = 0; ks < 4; ++ks) {
      s16x8 a0 = ldA(h0L, 0, ks, lo, hi), a1 = ldA(h0L, 1, ks, lo, hi);
#pragma unroll
      for (int g = 0; g < 4; ++g) {
        s16x8 bb = ldB(wL, g * 128 + colb, ks, lo, hi);
        acc[0][g] = mf(a0, bb, acc[0][g]);
        acc[1][g] = mf(a1, bb, acc[1][g]);
      }
    }
    unsigned short hb[2][4];
#pragma unroll
    for (int rt = 0; rt < 2; ++rt)
#pragma unroll
      for (int r = 0; r < 4; ++r)
        hb[rt][r] = cellup(acc[rt][0][r], acc[rt][1][r], acc[rt][2][r], acc[rt][3][r], c0s[rt][r]);
    __syncthreads();  // everyone done reading old h0
#pragma unroll
    for (int rt = 0; rt < 2; ++rt)
#pragma unroll
      for (int r = 0; r < 4; ++r)
        storeH(h0L, rt * 16 + hi * 4 + r, colb + lo, hb[rt][r]);
    __syncthreads();

    // ---- layer 1: g = h0new@Wih1^T + h1@Whh1^T + b1
#pragma unroll
    for (int g = 0; g < 4; ++g) { acc[0][g] = splat4(b1[g]); acc[1][g] = splat4(b1[g]); }
#pragma unroll
    for (int s = 0; s < 8; ++s) {
      const char* src = (s < 4) ? h0L : h1L;
      int ks = s & 3;
      s16x8 a0 = ldA(src, 0, ks, lo, hi), a1 = ldA(src, 1, ks, lo, hi);
#pragma unroll
      for (int g = 0; g < 4; ++g) {
        s16x8 bb = (s < 4) ? wi1[g][ks] : wh1[g][ks];
        acc[0][g] = mf(a0, bb, acc[0][g]);
        acc[1][g] = mf(a1, bb, acc[1][g]);
      }
    }
#pragma unroll
    for (int rt = 0; rt < 2; ++rt)
#pragma unroll
      for (int r = 0; r < 4; ++r)
        hb[rt][r] = cellup(acc[rt][0][r], acc[rt][1][r], acc[rt][2][r], acc[rt][3][r], c1s[rt][r]);
    __syncthreads();
#pragma unroll
    for (int rt = 0; rt < 2; ++rt)
#pragma unroll
      for (int r = 0; r < 4; ++r)
        storeH(h1L, rt * 16 + hi * 4 + r, colb + lo, hb[rt][r]);
    __syncthreads();
  }

  // ================= restage for decoder =================
  // (h0L/h1L and c-registers already hold encoder-final states in place)
  stageWrow(dWhh0, wL, tid);
  if (tid < 64) {  // dec_in = x[:, 99, :2] (fp32)
    int r = tid >> 1, o = tid & 1;
    inpL[r * 2 + o] = x[(long long)(row0 + r) * 1600 + 1584 + o];
  }
  if (tid < 256) {
    int o = tid >> 7, k = tid & 127;
    *(unsigned short*)(fcwL + o * 256 + k * 2) = f2h(fcW[o * 128 + k]);
  }
  float dwx[4][2];
#pragma unroll
  for (int g = 0; g < 4; ++g) {
    int col = g * 128 + colb + lo;
    b0[g] = dbih0[col] + dbhh0[col];
    b1[g] = dbih1[col] + dbhh1[col];
    dwx[g][0] = dWih0[col * 2 + 0];
    dwx[g][1] = dWih0[col * 2 + 1];
#pragma unroll
    for (int s = 0; s < 4; ++s) {
      wi1[g][s] = ldWfrag128(dWih1, col, s, hi);
      wh1[g][s] = ldWfrag128(dWhh1, col, s, hi);
    }
  }
  float fb0 = fcb[0], fb1 = fcb[1];
  __syncthreads();

  // ================= decoder phase =================
  for (int t = 0; t < 60; ++t) {
    // ---- layer 0: g = inp@dWih0^T (VALU fp32, K=2) + h0@dWhh0^T + b0
    f32x4 acc[2][4];
#pragma unroll
    for (int rt = 0; rt < 2; ++rt)
#pragma unroll
      for (int r = 0; r < 4; ++r) {
        float2 ip = *(const float2*)(inpL + (rt * 16 + hi * 4 + r) * 2);
#pragma unroll
        for (int g = 0; g < 4; ++g)
          acc[rt][g][r] = b0[g] + ip.x * dwx[g][0] + ip.y * dwx[g][1];
      }
#pragma unroll
    for (int ks = 0; ks < 4; ++ks) {
      s16x8 a0 = ldA(h0L, 0, ks, lo, hi), a1 = ldA(h0L, 1, ks, lo, hi);
#pragma unroll
      for (int g = 0; g < 4; ++g) {
        s16x8 bb = ldB(wL, g * 128 + colb, ks, lo, hi);
        acc[0][g] = mf(a0, bb, acc[0][g]);
        acc[1][g] = mf(a1, bb, acc[1][g]);
      }
    }
    unsigned short hb[2][4];
#pragma unroll
    for (int rt = 0; rt < 2; ++rt)
#pragma unroll
      for (int r = 0; r < 4; ++r)
        hb[rt][r] = cellup(acc[rt][0][r], acc[rt][1][r], acc[rt][2][r], acc[rt][3][r], c0s[rt][r]);
    __syncthreads();
#pragma unroll
    for (int rt = 0; rt < 2; ++rt)
#pragma unroll
      for (int r = 0; r < 4; ++r)
        storeH(h0L, rt * 16 + hi * 4 + r, colb + lo, hb[rt][r]);
    __syncthreads();

    // ---- layer 1
#pragma unroll
    for (int g = 0; g < 4; ++g) { acc[0][g] = splat4(b1[g]); acc[1][g] = splat4(b1[g]); }
#pragma unroll
    for (int s = 0; s < 8; ++s) {
      const char* src = (s < 4) ? h0L : h1L;
      int ks = s & 3;
      s16x8 a0 = ldA(src, 0, ks, lo, hi), a1 = ldA(src, 1, ks, lo, hi);
#pragma unroll
      for (int g = 0; g < 4; ++g) {
        s16x8 bb = (s < 4) ? wi1[g][ks] : wh1[g][ks];
        acc[0][g] = mf(a0, bb, acc[0][g]);
        acc[1][g] = mf(a1, bb, acc[1][g]);
      }
    }
#pragma unroll
    for (int rt = 0; rt < 2; ++rt)
#pragma unroll
      for (int r = 0; r < 4; ++r)
        hb[rt][r] = cellup(acc[rt][0][r], acc[rt][1][r], acc[rt][2][r], acc[rt][3][r], c1s[rt][r]);
    __syncthreads();
#pragma unroll
    for (int rt = 0; rt < 2; ++rt)
#pragma unroll
      for (int r = 0; r < 4; ++r)
        storeH(h1L, rt * 16 + hi * 4 + r, colb + lo, hb[rt][r]);
    __syncthreads();

    // ---- FC head + feedback (waves 0,1: lane -> (row, o, k-half))
    if (w < 2) {
      int row = w * 16 + lo;
      int o = hi & 1, kh = hi >> 1;
      float sum = 0.f;
#pragma unroll
      for (int cc = 0; cc < 8; ++cc) {
        s16x8 hv = *(const s16x8*)(h1L + swz(row, kh * 8 + cc));
        s16x8 wv = *(const s16x8*)(fcwL + o * 256 + (kh * 8 + cc) * 16);
#pragma unroll
        for (int j = 0; j < 8; ++j) sum += h2f(hv[j]) * h2f(wv[j]);
      }
      sum += __shfl_xor(sum, 32, 64);
      if (l < 32) {
        float ov = sum + (o ? fb1 : fb0);
        inpL[row * 2 + o] = ov;  // fp32 feedback, matches reference carry
        out[((long long)(row0 + row) * 60 + t) * 2 + o] = ov;  // FP32 store
      }
    }
    __syncthreads();
  }
}

extern "C" void kernel_launch(void* const* d_in, const int* in_sizes, int n_in,
                              void* d_out, int out_size, void* d_ws, size_t ws_size,
                              hipStream_t stream) {
  (void)in_sizes; (void)n_in; (void)out_size; (void)d_ws; (void)ws_size;
  const float* x      = (const float*)d_in[0];
  // d_in[1] = target_len (60), hardcoded
  const float* eWih0  = (const float*)d_in[2];
  const float* eWhh0  = (const float*)d_in[3];
  const float* ebih0  = (const float*)d_in[4];
  const float* ebhh0  = (const float*)d_in[5];
  const float* eWih1  = (const float*)d_in[6];
  const float* eWhh1  = (const float*)d_in[7];
  const float* ebih1  = (const float*)d_in[8];
  const float* ebhh1  = (const float*)d_in[9];
  const float* dWih0  = (const float*)d_in[10];
  const float* dWhh0  = (const float*)d_in[11];
  const float* dbih0  = (const float*)d_in[12];
  const float* dbhh0  = (const float*)d_in[13];
  const float* dWih1  = (const float*)d_in[14];
  const float* dWhh1  = (const float*)d_in[15];
  const float* dbih1  = (const float*)d_in[16];
  const float* dbhh1  = (const float*)d_in[17];
  const float* fcW    = (const float*)d_in[18];
  const float* fcb    = (const float*)d_in[19];
  float* out          = (float*)d_out;

  hipFuncSetAttribute(reinterpret_cast<const void*>(fused_kernel),
                      hipFuncAttributeMaxDynamicSharedMemorySize, SMEM_BYTES);

  fused_kernel<<<256, 512, SMEM_BYTES, stream>>>(
      x, eWih0, eWhh0, ebih0, ebhh0, eWih1, eWhh1, ebih1, ebhh1,
      dWih0, dWhh0, dbih0, dbhh0, dWih1, dWhh1, dbih1, dbhh1,
      fcW, fcb, out);
}

// Round 11
// 1507.891 us; speedup vs baseline: 1.6989x; 1.6304x over previous
//
#include <hip/hip_runtime.h>
#include <hip/hip_bf16.h>

// R11: kill the in-loop weight conversion (diagnosed R7-R9 pathology: compiler
// rematerializes ldWfrag128 -> ~25 VALU/fragment/step). A prep kernel
// pre-converts all weights to fp16 ONCE into d_ws:
//   - layer-1 mats as fragment-ordered 16B records [mat][ks][col][hi]
//     (a wave's (g,ks) read = one contiguous 1KB segment from L2)
//   - W_hh0 as pre-swizzled LDS images (main kernel: linear 16B copies)
//   - Wih0 x-projection fragments (K=16 zero-padded to 32)
// Main loop: fragment use = ONE global_load_dwordx4 (L2-hit), zero VALU.
// asm-launder on the base offset defeats LICM (no 128-reg hoist -> no spill).
// Arithmetic identical to the passing R7/R9 path (fp16 weights/h, fp32 c).

using s16x8 = __attribute__((ext_vector_type(8))) short;
using h16x8 = __attribute__((ext_vector_type(8))) _Float16;
using f32x4 = __attribute__((ext_vector_type(4))) float;

#define DEV static __device__ __forceinline__

DEV unsigned short f2h(float f) {
  _Float16 h = (_Float16)f;  // RNE
  return __builtin_bit_cast(unsigned short, h);
}
DEV float h2f(short h) {
  return (float)__builtin_bit_cast(_Float16, (unsigned short)h);
}
DEV float sigm(float v) { return 1.0f / (1.0f + __expf(-v)); }
DEV float tanh_(float v) {
  float e = __expf(-2.0f * fabsf(v));
  float r = (1.0f - e) / (1.0f + e);
  return v < 0.0f ? -r : r;
}
DEV f32x4 mf(s16x8 a, s16x8 b, f32x4 c) {
  return __builtin_amdgcn_mfma_f32_16x16x32_f16(
      __builtin_bit_cast(h16x8, a), __builtin_bit_cast(h16x8, b), c, 0, 0, 0);
}
DEV f32x4 splat4(float v) { f32x4 r = {v, v, v, v}; return r; }

// byte offset into a [rows][128] fp16 buffer; 16 slots of 8 fp16 per row,
// slot XOR-swizzled by row&15 -> conflict-free ds_read_b128 down columns.
DEV int swz(int row, int slot) { return row * 256 + (((slot ^ row) & 15) << 4); }

// A fragment from a swizzled [32][128] fp16 h-buffer
DEV s16x8 ldA(const char* buf, int rt, int ks, int lo, int hi) {
  return *(const s16x8*)(buf + swz(rt * 16 + lo, ks * 4 + hi));
}
// B fragment from the LDS-resident weight matrix
DEV s16x8 ldB(const char* wlds, int colbase, int ks, int lo, int hi) {
  return *(const s16x8*)(wlds + swz(colbase + lo, ks * 4 + hi));
}
// scatter one fp16 h value into the swizzled h-buffer
DEV void storeH(char* buf, int row, int col, unsigned short v) {
  int addr = row * 256 + ((((col >> 3) ^ row) & 15) << 4) + (col & 7) * 2;
  *(unsigned short*)(buf + addr) = v;
}
// LSTM pointwise: gates (i,f,g,o) -> update c, return fp16(h)
DEV unsigned short cellup(float gi, float gf, float gg, float go, float& c) {
  float i = sigm(gi), f = sigm(gf), g2 = tanh_(gg), o = sigm(go);
  c = f * c + i * g2;
  return f2h(o * tanh_(c));
}

// ---- d_ws layout (bytes) ----
// WF: 4 mats x 128KB, frag addr = m*131072 + ks*32768 + col*64 + hi*16
//     m: 0=eWih1 1=eWhh1 2=dWih1 3=dWhh1
// W0 images (pre-swizzled LDS copies): eWhh0 @524288, dWhh0 @655360 (128KB ea)
// WX (eWih0 K=16 padded frags): @786432, addr = col*64 + hi*16 (32KB)
#define WS_W0E 524288
#define WS_W0D 655360
#define WS_WX  786432

__global__ void prep_kernel(
    const float* __restrict__ eWih0, const float* __restrict__ eWhh0,
    const float* __restrict__ eWih1, const float* __restrict__ eWhh1,
    const float* __restrict__ dWhh0, const float* __restrict__ dWih1,
    const float* __restrict__ dWhh1, char* __restrict__ ws) {
  int idx = blockIdx.x * 256 + threadIdx.x;
  if (idx < 32768) {  // layer-1 fragment records
    int m = idx >> 13, r = idx & 8191;
    int col = r >> 4, ks = (r >> 2) & 3, hi = r & 3;
    const float* W = (m == 0) ? eWih1 : (m == 1) ? eWhh1 : (m == 2) ? dWih1 : dWhh1;
    const float* p = W + col * 128 + ks * 32 + hi * 8;
    s16x8 v;
#pragma unroll
    for (int j = 0; j < 8; ++j) v[j] = (short)f2h(p[j]);
    *(s16x8*)(ws + m * 131072 + ks * 32768 + col * 64 + hi * 16) = v;
  } else if (idx < 49152) {  // W_hh0 pre-swizzled images
    int r2 = idx - 32768;
    int m = r2 >> 13, rr = r2 & 8191;
    int row = rr >> 4, s = rr & 15;
    const float* W = m ? dWhh0 : eWhh0;
    const float* p = W + row * 128 + s * 8;
    s16x8 v;
#pragma unroll
    for (int j = 0; j < 8; ++j) v[j] = (short)f2h(p[j]);
    *(s16x8*)(ws + (m ? WS_W0D : WS_W0E) + row * 256 + (((s ^ row) & 15) << 4)) = v;
  } else if (idx < 51200) {  // x-projection fragments (K=16 -> 32 zero-pad)
    int r3 = idx - 49152;
    int col = r3 >> 2, hi = r3 & 3;
    s16x8 v;
#pragma unroll
    for (int j = 0; j < 8; ++j) v[j] = 0;
    if (hi < 2) {
      const float* p = eWih0 + col * 16 + hi * 8;
#pragma unroll
      for (int j = 0; j < 8; ++j) v[j] = (short)f2h(p[j]);
    }
    *(s16x8*)(ws + WS_WX + col * 64 + hi * 16) = v;
  }
}

#define SMEM_BYTES 150784

__global__ __launch_bounds__(512, 2) void fused_kernel(
    const float* __restrict__ x,
    const float* __restrict__ ebih0, const float* __restrict__ ebhh0,
    const float* __restrict__ ebih1, const float* __restrict__ ebhh1,
    const float* __restrict__ dWih0,
    const float* __restrict__ dbih0, const float* __restrict__ dbhh0,
    const float* __restrict__ dbih1, const float* __restrict__ dbhh1,
    const float* __restrict__ fcW, const float* __restrict__ fcb,
    const char* __restrict__ ws, float* __restrict__ out) {
  extern __shared__ char smem[];
  char* wL   = smem;                       // 131072: W_hh0 swizzled
  char* h0L  = smem + 131072;              // 8192
  char* h1L  = smem + 139264;              // 8192
  char* xL   = smem + 147456;              // 2560 (32 rows * 80B, K pad to 32)
  float* inpL = (float*)(smem + 150016);   // 256: 32x2 fp32 decoder feedback
  char* fcwL = smem + 150272;              // 512: 2x128 fp16

  const int tid = threadIdx.x;
  const int w = tid >> 6, l = tid & 63, lo = l & 15, hi = l >> 4;
  const int row0 = blockIdx.x * 32;
  const int colb = w * 16;
  // per-thread fragment byte offset within a [ks][col][hi] record block
  const int obase = (colb + lo) * 64 + hi * 16;

  // ================= encoder phase =================
  {  // stage pre-swizzled W_hh0 image -> LDS (linear 16B copies)
    const int4* src = (const int4*)(ws + WS_W0E);
    int4* dst = (int4*)wL;
    for (int i = tid; i < 8192; i += 512) dst[i] = src[i];
  }
  {  // zero h0,h1 and x buffer (incl. K-padding)
    int4 z = make_int4(0, 0, 0, 0);
    int4* p = (int4*)h0L;
    for (int i = tid; i < 1024; i += 512) p[i] = z;
    int4* q = (int4*)xL;
    for (int i = tid; i < 160; i += 512) q[i] = z;
  }

  float b0[4], b1[4];
  s16x8 wx0[4];
#pragma unroll
  for (int g = 0; g < 4; ++g) {
    int col = g * 128 + colb + lo;
    b0[g] = ebih0[col] + ebhh0[col];
    b1[g] = ebih1[col] + ebhh1[col];
    wx0[g] = *(const s16x8*)(ws + WS_WX + g * 8192 + obase);
  }

  float c0s[2][4], c1s[2][4];
#pragma unroll
  for (int rt = 0; rt < 2; ++rt)
#pragma unroll
    for (int r = 0; r < 4; ++r) { c0s[rt][r] = 0.f; c1s[rt][r] = 0.f; }
  __syncthreads();

  const int xr = tid >> 4, xf = tid & 15;
  const float* xrow = x + (long long)(row0 + xr) * 1600 + xf;
  float xv = xrow[0];

  for (int t = 0; t < 100; ++t) {
    *(unsigned short*)(xL + xr * 80 + xf * 2) = f2h(xv);
    __syncthreads();
    if (t < 99) xv = xrow[(t + 1) * 16];  // prefetch under compute

    // ---- layer 0: g = x@Wih0^T + h0@Whh0^T + b0
    f32x4 acc[2][4];
#pragma unroll
    for (int g = 0; g < 4; ++g) { acc[0][g] = splat4(b0[g]); acc[1][g] = splat4(b0[g]); }
    {
      s16x8 a0 = *(const s16x8*)(xL + lo * 80 + hi * 16);
      s16x8 a1 = *(const s16x8*)(xL + (16 + lo) * 80 + hi * 16);
#pragma unroll
      for (int g = 0; g < 4; ++g) {
        acc[0][g] = mf(a0, wx0[g], acc[0][g]);
        acc[1][g] = mf(a1, wx0[g], acc[1][g]);
      }
    }
#pragma unroll
    for (int ks = 0; ks < 4; ++ks) {
      s16x8 a0 = ldA(h0L, 0, ks, lo, hi), a1 = ldA(h0L, 1, ks, lo, hi);
#pragma unroll
      for (int g = 0; g < 4; ++g) {
        s16x8 bb = ldB(wL, g * 128 + colb, ks, lo, hi);
        acc[0][g] = mf(a0, bb, acc[0][g]);
        acc[1][g] = mf(a1, bb, acc[1][g]);
      }
    }
    unsigned short hb[2][4];
#pragma unroll
    for (int rt = 0; rt < 2; ++rt)
#pragma unroll
      for (int r = 0; r < 4; ++r)
        hb[rt][r] = cellup(acc[rt][0][r], acc[rt][1][r], acc[rt][2][r], acc[rt][3][r], c0s[rt][r]);
    __syncthreads();  // everyone done reading old h0
#pragma unroll
    for (int rt = 0; rt < 2; ++rt)
#pragma unroll
      for (int r = 0; r < 4; ++r)
        storeH(h0L, rt * 16 + hi * 4 + r, colb + lo, hb[rt][r]);
    __syncthreads();

    // ---- layer 1: g = h0new@Wih1^T + h1@Whh1^T + b1 (frags from L2)
    int lfoff = 0;
    asm("" : "+s"(lfoff));  // defeat LICM: no 128-reg hoist, no spill
    const char* WFa = ws + lfoff;  // encoder mats 0/1
#pragma unroll
    for (int g = 0; g < 4; ++g) { acc[0][g] = splat4(b1[g]); acc[1][g] = splat4(b1[g]); }
#pragma unroll
    for (int s = 0; s < 8; ++s) {
      const char* src = (s < 4) ? h0L : h1L;
      int ks = s & 3;
      const char* wfb = WFa + (s < 4 ? 0 : 131072) + ks * 32768;
      s16x8 a0 = ldA(src, 0, ks, lo, hi), a1 = ldA(src, 1, ks, lo, hi);
#pragma unroll
      for (int g = 0; g < 4; ++g) {
        s16x8 bb = *(const s16x8*)(wfb + g * 8192 + obase);
        acc[0][g] = mf(a0, bb, acc[0][g]);
        acc[1][g] = mf(a1, bb, acc[1][g]);
      }
    }
#pragma unroll
    for (int rt = 0; rt < 2; ++rt)
#pragma unroll
      for (int r = 0; r < 4; ++r)
        hb[rt][r] = cellup(acc[rt][0][r], acc[rt][1][r], acc[rt][2][r], acc[rt][3][r], c1s[rt][r]);
    __syncthreads();
#pragma unroll
    for (int rt = 0; rt < 2; ++rt)
#pragma unroll
      for (int r = 0; r < 4; ++r)
        storeH(h1L, rt * 16 + hi * 4 + r, colb + lo, hb[rt][r]);
    __syncthreads();
  }

  // ================= restage for decoder =================
  {  // stage dWhh0 image -> LDS
    const int4* src = (const int4*)(ws + WS_W0D);
    int4* dst = (int4*)wL;
    for (int i = tid; i < 8192; i += 512) dst[i] = src[i];
  }
  if (tid < 64) {  // dec_in = x[:, 99, :2] (fp32)
    int r = tid >> 1, o = tid & 1;
    inpL[r * 2 + o] = x[(long long)(row0 + r) * 1600 + 1584 + o];
  }
  if (tid < 256) {
    int o = tid >> 7, k = tid & 127;
    *(unsigned short*)(fcwL + o * 256 + k * 2) = f2h(fcW[o * 128 + k]);
  }
  float dwx[4][2];
#pragma unroll
  for (int g = 0; g < 4; ++g) {
    int col = g * 128 + colb + lo;
    b0[g] = dbih0[col] + dbhh0[col];
    b1[g] = dbih1[col] + dbhh1[col];
    dwx[g][0] = dWih0[col * 2 + 0];
    dwx[g][1] = dWih0[col * 2 + 1];
  }
  float fb0 = fcb[0], fb1 = fcb[1];
  __syncthreads();

  // ================= decoder phase =================
  for (int t = 0; t < 60; ++t) {
    // ---- layer 0: g = inp@dWih0^T (VALU fp32, K=2) + h0@dWhh0^T + b0
    f32x4 acc[2][4];
#pragma unroll
    for (int rt = 0; rt < 2; ++rt)
#pragma unroll
      for (int r = 0; r < 4; ++r) {
        float2 ip = *(const float2*)(inpL + (rt * 16 + hi * 4 + r) * 2);
#pragma unroll
        for (int g = 0; g < 4; ++g)
          acc[rt][g][r] = b0[g] + ip.x * dwx[g][0] + ip.y * dwx[g][1];
      }
#pragma unroll
    for (int ks = 0; ks < 4; ++ks) {
      s16x8 a0 = ldA(h0L, 0, ks, lo, hi), a1 = ldA(h0L, 1, ks, lo, hi);
#pragma unroll
      for (int g = 0; g < 4; ++g) {
        s16x8 bb = ldB(wL, g * 128 + colb, ks, lo, hi);
        acc[0][g] = mf(a0, bb, acc[0][g]);
        acc[1][g] = mf(a1, bb, acc[1][g]);
      }
    }
    unsigned short hb[2][4];
#pragma unroll
    for (int rt = 0; rt < 2; ++rt)
#pragma unroll
      for (int r = 0; r < 4; ++r)
        hb[rt][r] = cellup(acc[rt][0][r], acc[rt][1][r], acc[rt][2][r], acc[rt][3][r], c0s[rt][r]);
    __syncthreads();
#pragma unroll
    for (int rt = 0; rt < 2; ++rt)
#pragma unroll
      for (int r = 0; r < 4; ++r)
        storeH(h0L, rt * 16 + hi * 4 + r, colb + lo, hb[rt][r]);
    __syncthreads();

    // ---- layer 1 (frags from L2, decoder mats 2/3)
    int lfoff = 0;
    asm("" : "+s"(lfoff));
    const char* WFa = ws + 262144 + lfoff;
#pragma unroll
    for (int g = 0; g < 4; ++g) { acc[0][g] = splat4(b1[g]); acc[1][g] = splat4(b1[g]); }
#pragma unroll
    for (int s = 0; s < 8; ++s) {
      const char* src = (s < 4) ? h0L : h1L;
      int ks = s & 3;
      const char* wfb = WFa + (s < 4 ? 0 : 131072) + ks * 32768;
      s16x8 a0 = ldA(src, 0, ks, lo, hi), a1 = ldA(src, 1, ks, lo, hi);
#pragma unroll
      for (int g = 0; g < 4; ++g) {
        s16x8 bb = *(const s16x8*)(wfb + g * 8192 + obase);
        acc[0][g] = mf(a0, bb, acc[0][g]);
        acc[1][g] = mf(a1, bb, acc[1][g]);
      }
    }
#pragma unroll
    for (int rt = 0; rt < 2; ++rt)
#pragma unroll
      for (int r = 0; r < 4; ++r)
        hb[rt][r] = cellup(acc[rt][0][r], acc[rt][1][r], acc[rt][2][r], acc[rt][3][r], c1s[rt][r]);
    __syncthreads();
#pragma unroll
    for (int rt = 0; rt < 2; ++rt)
#pragma unroll
      for (int r = 0; r < 4; ++r)
        storeH(h1L, rt * 16 + hi * 4 + r, colb + lo, hb[rt][r]);
    __syncthreads();

    // ---- FC head + feedback (waves 0,1: lane -> (row, o, k-half))
    if (w < 2) {
      int row = w * 16 + lo;
      int o = hi & 1, kh = hi >> 1;
      float sum = 0.f;
#pragma unroll
      for (int cc = 0; cc < 8; ++cc) {
        s16x8 hv = *(const s16x8*)(h1L + swz(row, kh * 8 + cc));
        s16x8 wv = *(const s16x8*)(fcwL + o * 256 + (kh * 8 + cc) * 16);
#pragma unroll
        for (int j = 0; j < 8; ++j) sum += h2f(hv[j]) * h2f(wv[j]);
      }
      sum += __shfl_xor(sum, 32, 64);
      if (l < 32) {
        float ov = sum + (o ? fb1 : fb0);
        inpL[row * 2 + o] = ov;  // fp32 feedback, matches reference carry
        out[((long long)(row0 + row) * 60 + t) * 2 + o] = ov;  // FP32 store
      }
    }
    __syncthreads();
  }
}

extern "C" void kernel_launch(void* const* d_in, const int* in_sizes, int n_in,
                              void* d_out, int out_size, void* d_ws, size_t ws_size,
                              hipStream_t stream) {
  (void)in_sizes; (void)n_in; (void)out_size; (void)ws_size;
  const float* x      = (const float*)d_in[0];
  // d_in[1] = target_len (60), hardcoded
  const float* eWih0  = (const float*)d_in[2];
  const float* eWhh0  = (const float*)d_in[3];
  const float* ebih0  = (const float*)d_in[4];
  const float* ebhh0  = (const float*)d_in[5];
  const float* eWih1  = (const float*)d_in[6];
  const float* eWhh1  = (const float*)d_in[7];
  const float* ebih1  = (const float*)d_in[8];
  const float* ebhh1  = (const float*)d_in[9];
  const float* dWih0  = (const float*)d_in[10];
  const float* dWhh0  = (const float*)d_in[11];
  const float* dbih0  = (const float*)d_in[12];
  const float* dbhh0  = (const float*)d_in[13];
  const float* dWih1  = (const float*)d_in[14];
  const float* dWhh1  = (const float*)d_in[15];
  const float* dbih1  = (const float*)d_in[16];
  const float* dbhh1  = (const float*)d_in[17];
  const float* fcW    = (const float*)d_in[18];
  const float* fcb    = (const float*)d_in[19];
  float* out          = (float*)d_out;
  char* ws            = (char*)d_ws;

  prep_kernel<<<200, 256, 0, stream>>>(eWih0, eWhh0, eWih1, eWhh1,
                                       dWhh0, dWih1, dWhh1, ws);

  hipFuncSetAttribute(reinterpret_cast<const void*>(fused_kernel),
                      hipFuncAttributeMaxDynamicSharedMemorySize, SMEM_BYTES);

  fused_kernel<<<256, 512, SMEM_BYTES, stream>>>(
      x, ebih0, ebhh0, ebih1, ebhh1, dWih0, dbih0, dbhh0, dbih1, dbhh1,
      fcW, fcb, ws, out);
}